// Round 2
// baseline (5158.309 us; speedup 1.0000x reference)
//
#include <hip/hip_runtime.h>
#include <hip/hip_bf16.h>

#define TT 512
#define BB 128
#define II 256
#define HH 512
#define OO 256

#define NGB 8     // batch groups
#define NGN 16    // N-slices per group
#define RB  16    // batch rows per group
#define NS  32    // hidden cols per slice

#define PRED_SZ (TT*OO)

typedef __attribute__((ext_vector_type(8))) short bf16x8;
typedef __attribute__((ext_vector_type(4))) float f32x4;
typedef __attribute__((ext_vector_type(4))) int   i32x4;

// workspace layout (bytes)
#define WS_G1   0                        // 8 ints (monotone: layer0 posts)
#define WS_G2   128                      // 8 ints (monotone: layer1 posts)
#define WS_H1   256                      // ring depth 4: [4][BB][HH] bf16 = 524288
#define WS_H2   (WS_H1 + 4*BB*HH*2)      // ring depth 2: [2][BB][HH] bf16 = 262144
#define WS_SAVE (WS_H2 + 2*BB*HH*2)      // [TT][HH] f32 = 1 MB
#define WS_ZERO WS_SAVE                  // zero counters + h rings each launch

__device__ __forceinline__ ushort f2bf(float f) {
  union { float f; unsigned u; } v; v.f = f;
  unsigned u = v.u;
  return (ushort)((u + 0x7FFFu + ((u >> 16) & 1u)) >> 16);   // RNE
}

__device__ __forceinline__ float fast_tanh(float x) {
  float cx = fminf(fmaxf(x, -30.f), 30.f);
  float t  = __builtin_amdgcn_exp2f(cx * 2.885390081777927f);  // e^(2x)
  return (t - 1.f) * __builtin_amdgcn_rcpf(t + 1.f);
}

// coherent (IF$-level) 16B load, bypasses L1/L2 — no cache maintenance needed
__device__ __forceinline__ i32x4 ld_coh16B(const ushort* p) {
  i32x4 r;
  asm volatile("global_load_dwordx4 %0, %1, off sc0 sc1"
               : "=v"(r) : "v"(p) : "memory");
  return r;
}
// coherent 2B store (write-through to IF$)
__device__ __forceinline__ void st_coh2B(ushort* p, ushort v) {
  unsigned vv = v;
  asm volatile("global_store_short %0, %1, off sc0 sc1"
               :: "v"(p), "v"(vv) : "memory");
}

__device__ __forceinline__ int g_load(int* a) {
  return __hip_atomic_load(a, __ATOMIC_RELAXED, __HIP_MEMORY_SCOPE_AGENT);
}
__device__ __forceinline__ void g_post(int* a) {
  __hip_atomic_fetch_add(a, 1, __ATOMIC_RELAXED, __HIP_MEMORY_SCOPE_AGENT);
}

__global__ __launch_bounds__(256, 1) void rnn_scan_kernel(
    const float* __restrict__ x,
    const float* __restrict__ Wih0, const float* __restrict__ bih0,
    const float* __restrict__ Whh0, const float* __restrict__ bhh0,
    const float* __restrict__ Wih1, const float* __restrict__ bih1,
    const float* __restrict__ Whh1, const float* __restrict__ bhh1,
    float* __restrict__ out, char* __restrict__ ws)
{
  // packed B-fragments: unit u (0..111) = {Wih0: 0..15, Whh0: 16..47, Wih1: 48..79, Whh1: 80..111}
  __shared__ ushort ldsW[112*64*8];        // 112 KiB
  __shared__ float bias0[NS];
  __shared__ float bias1[NS];

  int*    g1     = (int*)(ws + WS_G1);
  int*    g2     = (int*)(ws + WS_G2);
  ushort* h1buf  = (ushort*)(ws + WS_H1);
  ushort* h2buf  = (ushort*)(ws + WS_H2);
  float*  h2save = (float*)(ws + WS_SAVE);

  const int tid = threadIdx.x;
  const int gb  = blockIdx.x & 7;          // batch group
  const int gn  = blockIdx.x >> 3;         // N-slice
  const int n0  = gn * NS;

  // ---- one-time: pack weight slices (fp32 global -> bf16 LDS, fragment order) ----
  {
    const int lane = tid & 63;
    const int q    = tid >> 6;
    #pragma unroll 1
    for (int u = 0; u < 112; ++u) {
      const float* Wsrc; int Km; int ul;
      if (u < 16)      { Wsrc = Wih0; Km = II; ul = u; }
      else if (u < 48) { Wsrc = Whh0; Km = HH; ul = u - 16; }
      else if (u < 80) { Wsrc = Wih1; Km = HH; ul = u - 48; }
      else             { Wsrc = Whh1; Km = HH; ul = u - 80; }
      const int nk  = Km >> 5;
      const int ttl = ul / nk;
      const int kk  = ul - ttl*nk;
      const int n   = n0 + ttl*16 + (lane & 15);
      const int k   = kk*32 + (lane >> 4)*8 + q*2;
      const float2 wv = *(const float2*)(Wsrc + (size_t)n*Km + k);
      ushort2 b2; b2.x = f2bf(wv.x); b2.y = f2bf(wv.y);
      *(ushort2*)&ldsW[(u*64 + lane)*8 + q*2] = b2;
    }
    if (tid < NS) {
      bias0[tid] = bih0[n0+tid] + bhh0[n0+tid];
      bias1[tid] = bih1[n0+tid] + bhh1[n0+tid];
    }
  }
  __syncthreads();

  const int w     = tid >> 6;
  const int lane  = tid & 63;
  const int ttile = w & 1;                 // 16-col tile within the 32-col slice
  const int layer = w >> 1;                // waves 0,1 -> layer0; 2,3 -> layer1
  const int kq    = lane >> 4;
  const int rowg  = gb*RB + (lane & 15);
  const int c     = lane & 15;

  int s1 = 0, s2 = 0;                      // cached counter values (monotone)

  if (layer == 0) {
    // ---------------- layer 0 self-chain: h1[p] = tanh(x W0^T + h1[p-1] W1^T + b) ----------------
    for (int p = 0; p < TT; ++p) {
      // x load + bf16 pack — independent of sync, done before the poll
      bf16x8 ax[8];
      {
        const float* xp = x + ((size_t)p*BB + rowg)*II + kq*8;
        f32x4 xf[16];
        #pragma unroll
        for (int kk = 0; kk < 8; ++kk) {
          xf[2*kk]   = *(const f32x4*)(xp + kk*32);
          xf[2*kk+1] = *(const f32x4*)(xp + kk*32 + 4);
        }
        #pragma unroll
        for (int kk = 0; kk < 8; ++kk)
          #pragma unroll
          for (int j = 0; j < 4; ++j) {
            ax[kk][j]   = (short)f2bf(xf[2*kk][j]);
            ax[kk][j+4] = (short)f2bf(xf[2*kk+1][j]);
          }
      }
      // wait: h1[p-1] complete (g1 >= 32p); h2[p-4] consumed (g2 >= 32(p-3))
      if (p >= 1 && s1 < 32*p)       { do { s1 = g_load(&g1[gb]); } while (s1 < 32*p); }
      if (p >= 4 && s2 < 32*(p-3))   { do { s2 = g_load(&g2[gb]); } while (s2 < 32*(p-3)); }
      asm volatile("" ::: "memory");

      f32x4 acc = {0.f,0.f,0.f,0.f};
      i32x4 af[16];
      if (p >= 1) {
        const ushort* ap = h1buf + ((size_t)((p-1)&3)*BB + rowg)*HH + kq*8;
        #pragma unroll
        for (int kk = 0; kk < 16; ++kk) af[kk] = ld_coh16B(ap + kk*32);
      }
      // x MFMAs issue under the shadow of the coherent loads
      #pragma unroll
      for (int kk = 0; kk < 8; ++kk) {
        const bf16x8 b = *(const bf16x8*)&ldsW[((0 + ttile*8 + kk)*64 + lane)*8];
        acc = __builtin_amdgcn_mfma_f32_16x16x32_bf16(ax[kk], b, acc, 0, 0, 0);
      }
      if (p >= 1) {
        asm volatile("s_waitcnt vmcnt(0)" ::: "memory");
        __builtin_amdgcn_sched_barrier(0);
        #pragma unroll
        for (int kk = 0; kk < 16; ++kk) {
          const bf16x8 b = *(const bf16x8*)&ldsW[((16 + ttile*16 + kk)*64 + lane)*8];
          acc = __builtin_amdgcn_mfma_f32_16x16x32_bf16(__builtin_bit_cast(bf16x8, af[kk]), b, acc, 0, 0, 0);
        }
      }
      const float bv = bias0[ttile*16 + c];
      ushort* dst = h1buf + (size_t)(p&3)*BB*HH;
      const int col = n0 + ttile*16 + c;
      #pragma unroll
      for (int j = 0; j < 4; ++j) {
        const int r = gb*16 + kq*4 + j;
        const float v = fast_tanh(acc[j] + bv);
        st_coh2B(dst + (size_t)r*HH + col, f2bf(v));
        if (p == TT-1) out[PRED_SZ + (size_t)r*HH + col] = v;   // h_final[0]
      }
      asm volatile("s_waitcnt vmcnt(0)" ::: "memory");
      if (lane == 0) g_post(&g1[gb]);
    }
  } else {
    // ---------------- layer 1: h2[p-1] = tanh(h1[p-1] W_ih1^T + h2[p-2] W_hh1^T + b) ----------------
    for (int p = 1; p <= TT; ++p) {
      if (s1 < 32*p)                 { do { s1 = g_load(&g1[gb]); } while (s1 < 32*p); }
      if (p >= 2 && s2 < 32*(p-1))   { do { s2 = g_load(&g2[gb]); } while (s2 < 32*(p-1)); }
      asm volatile("" ::: "memory");

      i32x4 af[16], a2[16];
      const ushort* ap  = h1buf + ((size_t)((p-1)&3)*BB + rowg)*HH + kq*8;
      const ushort* a2p = h2buf + ((size_t)(p&1)*BB + rowg)*HH + kq*8;  // (p-2)&1 == p&1
      #pragma unroll
      for (int kk = 0; kk < 16; ++kk) {
        af[kk] = ld_coh16B(ap  + kk*32);
        a2[kk] = ld_coh16B(a2p + kk*32);
      }
      asm volatile("s_waitcnt vmcnt(0)" ::: "memory");
      __builtin_amdgcn_sched_barrier(0);

      f32x4 acc = {0.f,0.f,0.f,0.f};
      #pragma unroll
      for (int kk = 0; kk < 16; ++kk) {
        const bf16x8 b = *(const bf16x8*)&ldsW[((48 + ttile*16 + kk)*64 + lane)*8];
        acc = __builtin_amdgcn_mfma_f32_16x16x32_bf16(__builtin_bit_cast(bf16x8, af[kk]), b, acc, 0, 0, 0);
      }
      #pragma unroll
      for (int kk = 0; kk < 16; ++kk) {
        const bf16x8 b = *(const bf16x8*)&ldsW[((80 + ttile*16 + kk)*64 + lane)*8];
        acc = __builtin_amdgcn_mfma_f32_16x16x32_bf16(__builtin_bit_cast(bf16x8, a2[kk]), b, acc, 0, 0, 0);
      }
      const float bv = bias1[ttile*16 + c];
      ushort* dst = h2buf + (size_t)((p-1)&1)*BB*HH;
      const int col = n0 + ttile*16 + c;
      #pragma unroll
      for (int j = 0; j < 4; ++j) {
        const int r = gb*16 + kq*4 + j;
        const float v = fast_tanh(acc[j] + bv);
        st_coh2B(dst + (size_t)r*HH + col, f2bf(v));
        if (r == BB-1) h2save[(size_t)(p-1)*HH + col] = v;       // trajectory of batch row 127
        if (p == TT) out[PRED_SZ + BB*HH + (size_t)r*HH + col] = v;  // h_final[1]
      }
      asm volatile("s_waitcnt vmcnt(0)" ::: "memory");
      if (lane == 0) g_post(&g2[gb]);
    }
  }
}

__global__ __launch_bounds__(256) void rnn_pred_kernel(
    const float* __restrict__ Wfc, const float* __restrict__ bfc,
    const float* __restrict__ h2save, float* __restrict__ out)
{
  __shared__ float hs[HH];
  const int t = blockIdx.x;
  for (int i = threadIdx.x; i < HH; i += 256) hs[i] = h2save[(size_t)t*HH + i];
  __syncthreads();
  const int o = threadIdx.x;
  const f32x4* wr = (const f32x4*)(Wfc + (size_t)o*HH);
  f32x4 s = {0.f,0.f,0.f,0.f};
  #pragma unroll 8
  for (int k = 0; k < HH/4; ++k) {
    const f32x4 wv = wr[k];
    const f32x4 hv = *(const f32x4*)&hs[4*k];
    s += wv * hv;
  }
  out[(size_t)t*OO + o] = bfc[o] + s[0] + s[1] + s[2] + s[3];
}

extern "C" void kernel_launch(void* const* d_in, const int* in_sizes, int n_in,
                              void* d_out, int out_size, void* d_ws, size_t ws_size,
                              hipStream_t stream) {
  const float* x    = (const float*)d_in[0];
  const float* Wih0 = (const float*)d_in[1];
  const float* bih0 = (const float*)d_in[2];
  const float* Whh0 = (const float*)d_in[3];
  const float* bhh0 = (const float*)d_in[4];
  const float* Wih1 = (const float*)d_in[5];
  const float* bih1 = (const float*)d_in[6];
  const float* Whh1 = (const float*)d_in[7];
  const float* bhh1 = (const float*)d_in[8];
  const float* Wfc  = (const float*)d_in[9];
  const float* bfc  = (const float*)d_in[10];
  float* out = (float*)d_out;
  char*  ws  = (char*)d_ws;

  // zero counters + h rings (h1[-1]=0, h2[-1]=0) every launch — deterministic
  hipMemsetAsync(ws, 0, WS_ZERO, stream);

  rnn_scan_kernel<<<NGB*NGN, 256, 0, stream>>>(x, Wih0, bih0, Whh0, bhh0,
                                               Wih1, bih1, Whh1, bhh1, out, ws);
  rnn_pred_kernel<<<TT, 256, 0, stream>>>(Wfc, bfc, (const float*)(ws + WS_SAVE), out);
}

// Round 6
// 3911.876 us; speedup vs baseline: 1.3186x; 1.3186x over previous
//
#include <hip/hip_runtime.h>
#include <hip/hip_bf16.h>

#define TT 512
#define BB 128
#define II 256
#define HH 512
#define OO 256

#define NGB 8     // batch groups
#define NGN 16    // N-slices per group
#define NS  32    // hidden cols per slice

#define PRED_SZ (TT*OO)

typedef __attribute__((ext_vector_type(8))) short bf16x8;
typedef __attribute__((ext_vector_type(4))) float f32x4;
typedef __attribute__((ext_vector_type(4))) int   i32x4;
typedef __attribute__((ext_vector_type(2))) int   i32x2;

// workspace layout (bytes)
#define WS_F1   0                        // flag1[8][32] int (per layer0-wave posts)
#define WS_F2   1024                     // flag2[8][32] int (per layer1-wave posts)
#define WS_H1   2048                     // ring4: [4][BB][HH] bf16 = 524288
#define WS_H2   (WS_H1 + 4*BB*HH*2)      // ring2: [2][BB][HH] bf16 = 262144
#define WS_SAVE (WS_H2 + 2*BB*HH*2)      // [TT][HH] f32 = 1 MB (fully overwritten)
#define WS_ZERO WS_SAVE                  // zero flags + h rings each launch

__device__ __forceinline__ ushort f2bf(float f) {
  union { float f; unsigned u; } v; v.f = f;
  unsigned u = v.u;
  return (ushort)((u + 0x7FFFu + ((u >> 16) & 1u)) >> 16);   // RNE
}

__device__ __forceinline__ float fast_tanh(float x) {
  float cx = fminf(fmaxf(x, -30.f), 30.f);
  float t  = __builtin_amdgcn_exp2f(cx * 2.885390081777927f);  // e^(2x)
  return (t - 1.f) * __builtin_amdgcn_rcpf(t + 1.f);
}

// ---- IF$-coherent primitives (round-2 proven: sc0 sc1 both ways) ----
__device__ __forceinline__ i32x4 ld16(const ushort* p) {
  i32x4 r;
  asm volatile("global_load_dwordx4 %0, %1, off sc0 sc1" : "=v"(r) : "v"(p) : "memory");
  return r;
}
// plain cached 16B load (x input; read-only data)
__device__ __forceinline__ f32x4 ld16g(const float* p) {
  f32x4 r;
  asm volatile("global_load_dwordx4 %0, %1, off" : "=v"(r) : "v"(p));
  return r;
}
__device__ __forceinline__ void st8(ushort* p, i32x2 v) {
  asm volatile("global_store_dwordx2 %0, %1, off sc0 sc1" :: "v"(p), "v"(v) : "memory");
}
__device__ __forceinline__ void st_flag(int* p, int v) {
  asm volatile("global_store_dword %0, %1, off sc0 sc1" :: "v"(p), "v"(v) : "memory");
}
__device__ __forceinline__ int ld_flag(const int* p) {
  int r;
  asm volatile("global_load_dword %0, %1, off sc0 sc1\n\ts_waitcnt vmcnt(0)"
               : "=v"(r) : "v"(p) : "memory");
  return r;
}
#define WAIT_VM(N) asm volatile("s_waitcnt vmcnt(" #N ")" ::: "memory")

__global__ __launch_bounds__(256, 1) void rnn_scan_kernel(
    const float* __restrict__ x,
    const float* __restrict__ Wih0, const float* __restrict__ bih0,
    const float* __restrict__ Whh0, const float* __restrict__ bhh0,
    const float* __restrict__ Wih1, const float* __restrict__ bih1,
    const float* __restrict__ Whh1, const float* __restrict__ bhh1,
    float* __restrict__ out, char* __restrict__ ws)
{
  // packed W fragments (consumed as MFMA *A* operand):
  // unit u (0..111) = {Wih0: 0..15, Whh0: 16..47, Wih1: 48..79, Whh1: 80..111}
  // ldsW[(u*64 + lane)*8 + j] = W[n0 + tile*16 + (lane&15)][kk*32 + (lane>>4)*8 + j]
  __shared__ ushort ldsW[112*64*8];        // 112 KiB
  __shared__ float bias0[NS];
  __shared__ float bias1[NS];

  int*    flag1  = (int*)(ws + WS_F1);
  int*    flag2  = (int*)(ws + WS_F2);
  ushort* h1buf  = (ushort*)(ws + WS_H1);
  ushort* h2buf  = (ushort*)(ws + WS_H2);
  float*  h2save = (float*)(ws + WS_SAVE);

  const int tid  = threadIdx.x;
  const int bid  = blockIdx.x;
  const int gb   = bid & 7;                // batch group
  const int gn   = bid >> 3;               // N-slice
  const int n0   = gn * NS;
  const int lane = tid & 63;

  // ---- one-time: pack weight slices (fp32 global -> bf16 LDS, fragment order) ----
  {
    const int q = tid >> 6;
    #pragma unroll 1
    for (int u = 0; u < 112; ++u) {
      const float* Wsrc; int Km; int ul;
      if (u < 16)      { Wsrc = Wih0; Km = II; ul = u; }
      else if (u < 48) { Wsrc = Whh0; Km = HH; ul = u - 16; }
      else if (u < 80) { Wsrc = Wih1; Km = HH; ul = u - 48; }
      else             { Wsrc = Whh1; Km = HH; ul = u - 80; }
      const int nk  = Km >> 5;
      const int ttl = ul / nk;
      const int kk  = ul - ttl*nk;
      const int n   = n0 + ttl*16 + (lane & 15);
      const int k   = kk*32 + (lane >> 4)*8 + q*2;
      const float2 wv = *(const float2*)(Wsrc + (size_t)n*Km + k);
      ushort2 b2; b2.x = f2bf(wv.x); b2.y = f2bf(wv.y);
      *(ushort2*)&ldsW[(u*64 + lane)*8 + q*2] = b2;
    }
    if (tid < NS) {
      bias0[tid] = bih0[n0+tid] + bhh0[n0+tid];
      bias1[tid] = bih1[n0+tid] + bhh1[n0+tid];
    }
  }
  __syncthreads();

  const int w     = tid >> 6;
  const int ttile = w & 1;                 // 16-col tile within the 32-col slice
  const int layer = w >> 1;                // waves 0,1 -> layer0; 2,3 -> layer1
  const int kq    = lane >> 4;
  const int c     = lane & 15;
  const int rowg  = gb*16 + c;             // batch row (loads AND stores)
  const int fl32  = lane & 31;
  const int nn    = ttile*16 + kq*4;       // this lane's first n-col within slice
  int* f1g = flag1 + gb*32;
  int* f2g = flag2 + gb*32;
  const int myf = gn*2 + ttile;

  if (layer == 0) {
    // ======== layer 0 self-chain: h1[p] = tanh(x[p] Wih0^T + h1[p-1] Whh0^T + b) ========
    // prologue: x-partial for p=0
    f32x4 xacc = {0.f,0.f,0.f,0.f};
    {
      const float* xp = x + (size_t)rowg*II + kq*8;
      f32x4 xv[16];
      #pragma unroll
      for (int kk = 0; kk < 8; ++kk) {
        xv[2*kk]   = ld16g(xp + kk*32);
        xv[2*kk+1] = ld16g(xp + kk*32 + 4);
      }
      WAIT_VM(0);
      __builtin_amdgcn_sched_barrier(0);
      #pragma unroll
      for (int kk = 0; kk < 8; ++kk) {
        bf16x8 a;
        #pragma unroll
        for (int j = 0; j < 4; ++j) {
          a[j]   = (short)f2bf(xv[2*kk][j]);
          a[j+4] = (short)f2bf(xv[2*kk+1][j]);
        }
        const bf16x8 wf = *(const bf16x8*)&ldsW[((ttile*8 + kk)*64 + lane)*8];
        xacc = __builtin_amdgcn_mfma_f32_16x16x32_bf16(wf, a, xacc, 0, 0, 0);
      }
    }

    int vf1 = 0, vf2 = 0;
    for (int p = 0; p < TT; ++p) {
      // polls first (nothing outstanding; ld_flag embeds vmcnt(0))
      if (p >= 1 && !__all(vf1 >= p)) {
        do { vf1 = ld_flag(f1g + fl32); } while (!__all(vf1 >= p));
      }
      if (p >= 4 && !__all(vf2 >= p-3)) {    // ring slack: h1[p-4] consumed
        do { __builtin_amdgcn_s_sleep(1); vf2 = ld_flag(f2g + fl32); } while (!__all(vf2 >= p-3));
      }
      // issue h1[p-1] loads (IF$), then next-phase x loads (cached)
      i32x4 af[16];
      if (p >= 1) {
        const ushort* ap = h1buf + ((size_t)((p-1)&3)*BB + rowg)*HH + kq*8;
        #pragma unroll
        for (int kk = 0; kk < 16; ++kk) af[kk] = ld16(ap + kk*32);
      }
      const int pn = (p+1 < TT) ? (p+1) : (TT-1);
      f32x4 xv[16];
      {
        const float* xp = x + ((size_t)pn*BB + rowg)*II + kq*8;
        #pragma unroll
        for (int kk = 0; kk < 8; ++kk) {
          xv[2*kk]   = ld16g(xp + kk*32);
          xv[2*kk+1] = ld16g(xp + kk*32 + 4);
        }
      }
      f32x4 ac1 = {0.f,0.f,0.f,0.f}, ac2 = {0.f,0.f,0.f,0.f};
      if (p >= 1) {
        WAIT_VM(16);                       // af done; 16 x loads stay in flight
        __builtin_amdgcn_sched_barrier(0);
        #pragma unroll
        for (int kk = 0; kk < 8; ++kk) {
          const bf16x8 b0 = *(const bf16x8*)&ldsW[((16 + ttile*16 + kk)*64 + lane)*8];
          const bf16x8 b1 = *(const bf16x8*)&ldsW[((16 + ttile*16 + kk + 8)*64 + lane)*8];
          ac1 = __builtin_amdgcn_mfma_f32_16x16x32_bf16(b0, __builtin_bit_cast(bf16x8, af[kk]),   ac1, 0, 0, 0);
          ac2 = __builtin_amdgcn_mfma_f32_16x16x32_bf16(b1, __builtin_bit_cast(bf16x8, af[kk+8]), ac2, 0, 0, 0);
        }
      }
      // epilogue: D row = n-col (nn+j), D col = batch row -> 4 consecutive cols of one row
      float v0 = fast_tanh(xacc[0] + ac1[0] + ac2[0] + bias0[nn+0]);
      float v1 = fast_tanh(xacc[1] + ac1[1] + ac2[1] + bias0[nn+1]);
      float v2 = fast_tanh(xacc[2] + ac1[2] + ac2[2] + bias0[nn+2]);
      float v3 = fast_tanh(xacc[3] + ac1[3] + ac2[3] + bias0[nn+3]);
      i32x2 d;
      d[0] = (int)((unsigned)f2bf(v0) | ((unsigned)f2bf(v1) << 16));
      d[1] = (int)((unsigned)f2bf(v2) | ((unsigned)f2bf(v3) << 16));
      st8(h1buf + (size_t)(p&3)*BB*HH + (size_t)rowg*HH + n0 + nn, d);
      if (p == TT-1) {
        *(f32x4*)&out[PRED_SZ + (size_t)rowg*HH + n0 + nn] = (f32x4){v0,v1,v2,v3};  // h_final[0]
      }
      // x-pack + x-MFMAs for p+1 under the shadow of the store ack
      WAIT_VM(1);                          // x loads retired (in-order); store may stay in flight
      __builtin_amdgcn_sched_barrier(0);
      f32x4 xn = {0.f,0.f,0.f,0.f};
      #pragma unroll
      for (int kk = 0; kk < 8; ++kk) {
        bf16x8 a;
        #pragma unroll
        for (int j = 0; j < 4; ++j) {
          a[j]   = (short)f2bf(xv[2*kk][j]);
          a[j+4] = (short)f2bf(xv[2*kk+1][j]);
        }
        const bf16x8 wf = *(const bf16x8*)&ldsW[((ttile*8 + kk)*64 + lane)*8];
        xn = __builtin_amdgcn_mfma_f32_16x16x32_bf16(wf, a, xn, 0, 0, 0);
      }
      WAIT_VM(0);                          // h1 store at IF$
      if (lane == 0) st_flag(&f1g[myf], p + 1);
      xacc = xn;
    }
  } else {
    // ======== layer 1: h2[p-1] = tanh(h1[p-1] Wih1^T + h2[p-2] Whh1^T + b) ========
    int vf1 = 0, vf2 = 0;
    for (int p = 1; p <= TT; ++p) {
      if (!__all(vf1 >= p)) {
        do { vf1 = ld_flag(f1g + fl32); } while (!__all(vf1 >= p));
      }
      if (p >= 2 && !__all(vf2 >= p-1)) {
        do { vf2 = ld_flag(f2g + fl32); } while (!__all(vf2 >= p-1));
      }
      i32x4 af[16], a2[16];
      const ushort* ap  = h1buf + ((size_t)((p-1)&3)*BB + rowg)*HH + kq*8;
      const ushort* a2p = h2buf + ((size_t)(p&1)*BB + rowg)*HH + kq*8;  // (p-2)&1 == p&1
      #pragma unroll
      for (int kk = 0; kk < 16; ++kk) {
        af[kk] = ld16(ap  + kk*32);
        a2[kk] = ld16(a2p + kk*32);
      }
      WAIT_VM(0);
      __builtin_amdgcn_sched_barrier(0);

      f32x4 ac1 = {0.f,0.f,0.f,0.f}, ac2 = {0.f,0.f,0.f,0.f};
      f32x4 ac3 = {0.f,0.f,0.f,0.f}, ac4 = {0.f,0.f,0.f,0.f};
      #pragma unroll
      for (int kk = 0; kk < 8; ++kk) {
        const bf16x8 b0 = *(const bf16x8*)&ldsW[((48 + ttile*16 + kk)*64 + lane)*8];
        const bf16x8 b1 = *(const bf16x8*)&ldsW[((48 + ttile*16 + kk + 8)*64 + lane)*8];
        const bf16x8 b2 = *(const bf16x8*)&ldsW[((80 + ttile*16 + kk)*64 + lane)*8];
        const bf16x8 b3 = *(const bf16x8*)&ldsW[((80 + ttile*16 + kk + 8)*64 + lane)*8];
        ac1 = __builtin_amdgcn_mfma_f32_16x16x32_bf16(b0, __builtin_bit_cast(bf16x8, af[kk]),   ac1, 0, 0, 0);
        ac2 = __builtin_amdgcn_mfma_f32_16x16x32_bf16(b1, __builtin_bit_cast(bf16x8, af[kk+8]), ac2, 0, 0, 0);
        ac3 = __builtin_amdgcn_mfma_f32_16x16x32_bf16(b2, __builtin_bit_cast(bf16x8, a2[kk]),   ac3, 0, 0, 0);
        ac4 = __builtin_amdgcn_mfma_f32_16x16x32_bf16(b3, __builtin_bit_cast(bf16x8, a2[kk+8]), ac4, 0, 0, 0);
      }
      float v0 = fast_tanh(ac1[0] + ac2[0] + ac3[0] + ac4[0] + bias1[nn+0]);
      float v1 = fast_tanh(ac1[1] + ac2[1] + ac3[1] + ac4[1] + bias1[nn+1]);
      float v2 = fast_tanh(ac1[2] + ac2[2] + ac3[2] + ac4[2] + bias1[nn+2]);
      float v3 = fast_tanh(ac1[3] + ac2[3] + ac3[3] + ac4[3] + bias1[nn+3]);
      i32x2 d;
      d[0] = (int)((unsigned)f2bf(v0) | ((unsigned)f2bf(v1) << 16));
      d[1] = (int)((unsigned)f2bf(v2) | ((unsigned)f2bf(v3) << 16));
      st8(h2buf + (size_t)((p-1)&1)*BB*HH + (size_t)rowg*HH + n0 + nn, d);
      if (rowg == BB-1) {
        *(f32x4*)&h2save[(size_t)(p-1)*HH + n0 + nn] = (f32x4){v0,v1,v2,v3};   // row-127 trajectory
      }
      if (p == TT) {
        *(f32x4*)&out[PRED_SZ + BB*HH + (size_t)rowg*HH + n0 + nn] = (f32x4){v0,v1,v2,v3};  // h_final[1]
      }
      WAIT_VM(0);
      if (lane == 0) st_flag(&f2g[myf], p);
    }
  }
}

__global__ __launch_bounds__(256) void rnn_pred_kernel(
    const float* __restrict__ Wfc, const float* __restrict__ bfc,
    const float* __restrict__ h2save, float* __restrict__ out)
{
  __shared__ float hs[HH];
  const int t = blockIdx.x;
  for (int i = threadIdx.x; i < HH; i += 256) hs[i] = h2save[(size_t)t*HH + i];
  __syncthreads();
  const int o = threadIdx.x;
  const f32x4* wr = (const f32x4*)(Wfc + (size_t)o*HH);
  f32x4 s = {0.f,0.f,0.f,0.f};
  #pragma unroll 8
  for (int k = 0; k < HH/4; ++k) {
    const f32x4 wv = wr[k];
    const f32x4 hv = *(const f32x4*)&hs[4*k];
    s += wv * hv;
  }
  out[(size_t)t*OO + o] = bfc[o] + s[0] + s[1] + s[2] + s[3];
}

extern "C" void kernel_launch(void* const* d_in, const int* in_sizes, int n_in,
                              void* d_out, int out_size, void* d_ws, size_t ws_size,
                              hipStream_t stream) {
  const float* x    = (const float*)d_in[0];
  const float* Wih0 = (const float*)d_in[1];
  const float* bih0 = (const float*)d_in[2];
  const float* Whh0 = (const float*)d_in[3];
  const float* bhh0 = (const float*)d_in[4];
  const float* Wih1 = (const float*)d_in[5];
  const float* bih1 = (const float*)d_in[6];
  const float* Whh1 = (const float*)d_in[7];
  const float* bhh1 = (const float*)d_in[8];
  const float* Wfc  = (const float*)d_in[9];
  const float* bfc  = (const float*)d_in[10];
  float* out = (float*)d_out;
  char*  ws  = (char*)d_ws;

  // zero flags + both h rings every launch (h1[-1]=0, h2[-1]=0) — deterministic
  hipMemsetAsync(ws, 0, WS_ZERO, stream);

  rnn_scan_kernel<<<NGB*NGN, 256, 0, stream>>>(x, Wih0, bih0, Whh0, bhh0,
                                               Wih1, bih1, Whh1, bhh1, out, ws);
  rnn_pred_kernel<<<TT, 256, 0, stream>>>(Wfc, bfc, (const float*)(ws + WS_SAVE), out);
}